// Round 8
// baseline (1642.546 us; speedup 1.0000x reference)
//
#include <hip/hip_runtime.h>
#include <hip/hip_bf16.h>
#include <cstdint>
#include <cstddef>

#define B_   8192
#define DX_  512
#define DZ_  1024
#define DY_  256
#define T_   4
#define NN_  6

typedef float f32x4 __attribute__((ext_vector_type(4)));
typedef short s16x8 __attribute__((ext_vector_type(8)));
typedef __hip_bfloat16 bf16;

__device__ __forceinline__ void gload_lds16(const bf16* g, void* l) {
  __builtin_amdgcn_global_load_lds(
      (const __attribute__((address_space(1))) void*)g,
      (__attribute__((address_space(3))) void*)l,
      16, 0, 0);
}

__device__ __forceinline__ float bf2f(unsigned short u) {
  union { unsigned int i; float f; } cv; cv.i = ((unsigned int)u) << 16; return cv.f;
}
__device__ __forceinline__ float lo2f(unsigned int p) {
  union { unsigned int i; float f; } cv; cv.i = p << 16; return cv.f;
}
__device__ __forceinline__ float hi2f(unsigned int p) {
  union { unsigned int i; float f; } cv; cv.i = p & 0xffff0000u; return cv.f;
}
__device__ __forceinline__ unsigned int pk2(float a, float b) {
  bf16 x = __float2bfloat16(a), y = __float2bfloat16(b);
  return (unsigned int)*(unsigned short*)&x | ((unsigned int)*(unsigned short*)&y << 16);
}

__global__ void cvt_bf16_kernel(const float* __restrict__ in, bf16* __restrict__ out, int n4) {
  int i = blockIdx.x * blockDim.x + threadIdx.x;
  if (i >= n4) return;
  float4 v = ((const float4*)in)[i];
  ushort4 o;
  bf16 a0 = __float2bfloat16(v.x); o.x = *(unsigned short*)&a0;
  bf16 a1 = __float2bfloat16(v.y); o.y = *(unsigned short*)&a1;
  bf16 a2 = __float2bfloat16(v.z); o.z = *(unsigned short*)&a2;
  bf16 a3 = __float2bfloat16(v.w); o.w = *(unsigned short*)&a3;
  ((ushort4*)out)[i] = o;
}

__global__ void pack_bias_kernel(const float* __restrict__ a, const float* __restrict__ b,
                                 float* __restrict__ o) {
  int i = threadIdx.x;             // 512 threads
  o[i] = (i < DY_) ? a[i] : b[i - DY_];
}

// ---- band sync: 8 producer blocks per (step, band) slot. Release/acquire at agent
// scope -> correct independent of XCD placement (G16); id%8 round-robin puts all 8
// siblings of a band on one XCD (perf heuristic only).
__device__ __forceinline__ void band_arrive(unsigned int* flags, int idx) {
  __syncthreads();   // emits s_waitcnt vmcnt(0) lgkmcnt(0) -> all waves' stores done
  if (threadIdx.x == 0)
    __hip_atomic_fetch_add(&flags[idx], 1u, __ATOMIC_RELEASE, __HIP_MEMORY_SCOPE_AGENT);
}
__device__ __forceinline__ void band_wait(unsigned int* flags, int idx) {
  if (threadIdx.x == 0) {
    while (__hip_atomic_load(&flags[idx], __ATOMIC_RELAXED, __HIP_MEMORY_SCOPE_AGENT) < 8u)
      __builtin_amdgcn_s_sleep(2);
  }
  __syncthreads();
  if ((threadIdx.x & 63) == 0)   // one acquire (cache-inv) per wave
    (void)__hip_atomic_load(&flags[idx], __ATOMIC_ACQUIRE, __HIP_MEMORY_SCOPE_AGENT);
}

// ---- persistent fused recurrence. Grid (32 bands, 8 col-groups) = 256 blocks = 1/CU
// (144KB LDS forces exclusivity -> all co-resident, no deadlock). Each block owns a
// 256x128 output tile for every step. cx/cy addend tiles live in packed-bf16 VGPRs.
// K-loop = r7 core: BK=64, 3-buffer LDS, stage distance 2, counted vmcnt(6), two
// {ds_read -> s_barrier -> lgkmcnt(0) -> 16 MFMA} phases per K-tile, chunk-XOR swizzle
// (0 bank conflicts measured r2-r7).
__global__ __launch_bounds__(512, 1)
void trm_persist(const bf16* __restrict__ xs_b, const bf16* __restrict__ ysin_b,
                 bf16* __restrict__ z_a, bf16* __restrict__ z_b,
                 const bf16* __restrict__ Wx_b, const bf16* __restrict__ Wy_b,
                 const bf16* __restrict__ Wn_b,
                 const float* __restrict__ bx, const float* __restrict__ by,
                 const float* __restrict__ bn,
                 bf16* __restrict__ xse, bf16* __restrict__ ys,
                 unsigned int* __restrict__ flags)
{
  __shared__ __align__(16) char ldsc[3 * 49152];   // [buf][A 32KB | B 16KB]
  const int t    = threadIdx.x;
  const int lane = t & 63;
  const int wave = t >> 6;
  const int band = blockIdx.x;          // 0..31
  const int m0 = band * 256;
  const int n0 = blockIdx.y * 128;

  const int srow = t >> 3;                      // 0..63
  const int q    = (t & 7) ^ ((t >> 3) & 7);    // source-permuted 16B chunk
  const int wb   = wave * 1024;

  const int mo = (wave >> 1) * 64;
  const int no = (wave & 1) * 64;
  const int fr = lane & 15;
  const int g4 = lane >> 4;
  const int rb = g4 * 4;

  f32x4 acc[4][4];
  unsigned int cx_pk[4][4][2], cy_pk[4][4][2];
  s16x8 fa[4], fb[4];

  auto core = [&](const bf16* A, int lda, const bf16* W, int ldw, int NT) {
    const bf16* gA = A + (size_t)(m0 + srow) * lda + q * 8;
    const bf16* gB = W + (size_t)(n0 + srow) * ldw + q * 8;
    auto stage = [&](int kt) {
      char* base = ldsc + (kt % 3) * 49152;
      const int ko = kt << 6;
#pragma unroll
      for (int i = 0; i < 4; ++i)
        gload_lds16(gA + (size_t)(i * 64) * lda + ko, base + i * 8192 + wb);
#pragma unroll
      for (int i = 0; i < 2; ++i)
        gload_lds16(gB + (size_t)(i * 64) * ldw + ko, base + 32768 + i * 8192 + wb);
    };
    auto ldfrags = [&](int kt, int s) {
      const char* pA = ldsc + (kt % 3) * 49152;
      const char* pB = pA + 32768;
      const int cb = ((s * 4 + g4) ^ (fr & 7)) * 16;
#pragma unroll
      for (int f = 0; f < 4; ++f) fa[f] = *(const s16x8*)(pA + (mo + f * 16 + fr) * 128 + cb);
#pragma unroll
      for (int j = 0; j < 4; ++j) fb[j] = *(const s16x8*)(pB + (no + j * 16 + fr) * 128 + cb);
    };
    auto domfma = [&]() {
      __builtin_amdgcn_s_setprio(1);
#pragma unroll
      for (int f = 0; f < 4; ++f)
#pragma unroll
        for (int j = 0; j < 4; ++j)
          acc[f][j] = __builtin_amdgcn_mfma_f32_16x16x32_bf16(fa[f], fb[j], acc[f][j], 0, 0, 0);
      __builtin_amdgcn_s_setprio(0);
    };

    stage(0); stage(1);
    asm volatile("s_waitcnt vmcnt(6)" ::: "memory");
    __builtin_amdgcn_s_barrier();
    for (int kt = 0; kt < NT; ++kt) {
      ldfrags(kt, 0);
      __builtin_amdgcn_sched_barrier(0);
      __builtin_amdgcn_s_barrier();
      asm volatile("s_waitcnt lgkmcnt(0)" ::: "memory");
      __builtin_amdgcn_sched_barrier(0);
      domfma();
      ldfrags(kt, 1);
      if (kt + 2 < NT) stage(kt + 2);
      __builtin_amdgcn_sched_barrier(0);
      if (kt + 2 < NT) asm volatile("s_waitcnt vmcnt(6)" ::: "memory");
      else             asm volatile("s_waitcnt vmcnt(0)" ::: "memory");
      __builtin_amdgcn_s_barrier();
      asm volatile("s_waitcnt lgkmcnt(0)" ::: "memory");
      __builtin_amdgcn_sched_barrier(0);
      domfma();
    }
  };

  auto initbias = [&](const float* bias) {
    float bv[4];
#pragma unroll
    for (int j = 0; j < 4; ++j) bv[j] = bias ? bias[n0 + no + j * 16 + fr] : 0.f;
#pragma unroll
    for (int f = 0; f < 4; ++f)
#pragma unroll
      for (int j = 0; j < 4; ++j)
#pragma unroll
        for (int r = 0; r < 4; ++r) acc[f][j][r] = bv[j];
  };
  auto store_out = [&](bf16* o, int dotanh) {
#pragma unroll
    for (int f = 0; f < 4; ++f)
#pragma unroll
      for (int j = 0; j < 4; ++j) {
        const int n = n0 + no + j * 16 + fr;
#pragma unroll
        for (int r = 0; r < 4; ++r) {
          const int m = m0 + mo + f * 16 + rb + r;
          float v = acc[f][j][r];
          if (dotanh) { float e = __expf(2.f * v); v = 1.f - 2.f / (e + 1.f); }
          o[(size_t)m * DZ_ + n] = __float2bfloat16(v);
        }
      }
  };

  // ---- S0: xs_e = xs@Wx.T + bx  (flag 0)
  initbias(bx);
  core(xs_b, DX_, Wx_b, DX_, DX_ / 64);
  store_out(xse, 0);
  band_arrive(flags, 0 * 32 + band);

  // ---- S1: ys_e(init) = ys0@Wy.T + by  (flag 1)
  initbias(by);
  core(ysin_b, DY_, Wy_b, DY_, DY_ / 64);
  store_out(ys, 0);
  band_arrive(flags, 1 * 32 + band);

  // ---- S2: cx = xs_e@Wnx.T  (registers only)
  band_wait(flags, 0 * 32 + band);
  initbias(nullptr);
  core(xse, DZ_, Wn_b, 3 * DZ_, DZ_ / 64);
#pragma unroll
  for (int f = 0; f < 4; ++f)
#pragma unroll
    for (int j = 0; j < 4; ++j) {
      cx_pk[f][j][0] = pk2(acc[f][j][0], acc[f][j][1]);
      cx_pk[f][j][1] = pk2(acc[f][j][2], acc[f][j][3]);
    }

  int ysflag = 1, zf = 2, zprev = -1;
  bf16* zc = z_a;
  bf16* zn = z_b;
  for (int tt = 0; tt < T_; ++tt) {
    // cy = ys@Wny.T + bn  (registers only)
    band_wait(flags, ysflag * 32 + band);
    initbias(bn);
    core(ys, DZ_, Wn_b + DZ_, 3 * DZ_, DZ_ / 64);
#pragma unroll
    for (int f = 0; f < 4; ++f)
#pragma unroll
      for (int j = 0; j < 4; ++j) {
        cy_pk[f][j][0] = pk2(acc[f][j][0], acc[f][j][1]);
        cy_pk[f][j][1] = pk2(acc[f][j][2], acc[f][j][3]);
      }
    // 6 z-steps: z = tanh(cx + cy + z@Wnz.T)
    for (int i = 0; i < NN_; ++i) {
      if (zprev >= 0) band_wait(flags, zprev * 32 + band);
      else            __syncthreads();   // LDS reuse fence (initial z is stream-ordered)
#pragma unroll
      for (int f = 0; f < 4; ++f)
#pragma unroll
        for (int j = 0; j < 4; ++j) {
          acc[f][j][0] = lo2f(cy_pk[f][j][0]) + lo2f(cx_pk[f][j][0]);
          acc[f][j][1] = hi2f(cy_pk[f][j][0]) + hi2f(cx_pk[f][j][0]);
          acc[f][j][2] = lo2f(cy_pk[f][j][1]) + lo2f(cx_pk[f][j][1]);
          acc[f][j][3] = hi2f(cy_pk[f][j][1]) + hi2f(cx_pk[f][j][1]);
        }
      core(zc, DZ_, Wn_b + 2 * DZ_, 3 * DZ_, DZ_ / 64);
      store_out(zn, 1);
      band_arrive(flags, zf * 32 + band);
      zprev = zf; ++zf;
      bf16* tmp = zc; zc = zn; zn = tmp;
    }
    // ys = tanh(cy + z@Wnz.T)
    band_wait(flags, zprev * 32 + band);
#pragma unroll
    for (int f = 0; f < 4; ++f)
#pragma unroll
      for (int j = 0; j < 4; ++j) {
        acc[f][j][0] = lo2f(cy_pk[f][j][0]);
        acc[f][j][1] = hi2f(cy_pk[f][j][0]);
        acc[f][j][2] = lo2f(cy_pk[f][j][1]);
        acc[f][j][3] = hi2f(cy_pk[f][j][1]);
      }
    core(zc, DZ_, Wn_b + 2 * DZ_, 3 * DZ_, DZ_ / 64);
    store_out(ys, 1);
    band_arrive(flags, zf * 32 + band);
    ysflag = zf; ++zf;
  }
}

// ---- head GEMM (r7-proven): y|q = sigmoid(ys@[Wu;Wq].T + [bu;bq]), fp32 split store
__global__ __launch_bounds__(512, 2)
void head_gemm(const bf16* __restrict__ A,
               const bf16* __restrict__ W,
               const float* __restrict__ bias,
               float* __restrict__ out, float* __restrict__ out2)
{
  __shared__ __align__(16) char ldsc[3 * 49152];
  const int t    = threadIdx.x;
  const int lane = t & 63;
  const int wave = t >> 6;
  const int m0 = blockIdx.x * 256;
  const int n0 = blockIdx.y * 128;
  const int N = 2 * DY_, K = DZ_, lda = DZ_, ldw = DZ_;

  const int srow = t >> 3;
  const int q    = (t & 7) ^ ((t >> 3) & 7);
  const bf16* gA = A + (size_t)(m0 + srow) * lda + q * 8;
  const bf16* gB = W + (size_t)(n0 + srow) * ldw + q * 8;
  const int wb = wave * 1024;

  auto stage = [&](int kt) {
    char* base = ldsc + (kt % 3) * 49152;
    const int ko = kt << 6;
#pragma unroll
    for (int i = 0; i < 4; ++i)
      gload_lds16(gA + (size_t)(i * 64) * lda + ko, base + i * 8192 + wb);
#pragma unroll
    for (int i = 0; i < 2; ++i)
      gload_lds16(gB + (size_t)(i * 64) * ldw + ko, base + 32768 + i * 8192 + wb);
  };

  const int mo = (wave >> 1) * 64;
  const int no = (wave & 1) * 64;
  const int fr = lane & 15;
  const int g4 = lane >> 4;
  const int rb = g4 * 4;

  float bv[4];
#pragma unroll
  for (int j = 0; j < 4; ++j) bv[j] = bias[n0 + no + j * 16 + fr];
  f32x4 acc[4][4];
#pragma unroll
  for (int f = 0; f < 4; ++f)
#pragma unroll
    for (int j = 0; j < 4; ++j)
#pragma unroll
      for (int r = 0; r < 4; ++r) acc[f][j][r] = bv[j];

  s16x8 fa[4], fb[4];
  auto ldfrags = [&](int kt, int s) {
    const char* pA = ldsc + (kt % 3) * 49152;
    const char* pB = pA + 32768;
    const int cb = ((s * 4 + g4) ^ (fr & 7)) * 16;
#pragma unroll
    for (int f = 0; f < 4; ++f) fa[f] = *(const s16x8*)(pA + (mo + f * 16 + fr) * 128 + cb);
#pragma unroll
    for (int j = 0; j < 4; ++j) fb[j] = *(const s16x8*)(pB + (no + j * 16 + fr) * 128 + cb);
  };
  auto domfma = [&]() {
    __builtin_amdgcn_s_setprio(1);
#pragma unroll
    for (int f = 0; f < 4; ++f)
#pragma unroll
      for (int j = 0; j < 4; ++j)
        acc[f][j] = __builtin_amdgcn_mfma_f32_16x16x32_bf16(fa[f], fb[j], acc[f][j], 0, 0, 0);
    __builtin_amdgcn_s_setprio(0);
  };

  const int NT = K >> 6;
  stage(0); stage(1);
  asm volatile("s_waitcnt vmcnt(6)" ::: "memory");
  __builtin_amdgcn_s_barrier();
  for (int kt = 0; kt < NT; ++kt) {
    ldfrags(kt, 0);
    __builtin_amdgcn_sched_barrier(0);
    __builtin_amdgcn_s_barrier();
    asm volatile("s_waitcnt lgkmcnt(0)" ::: "memory");
    __builtin_amdgcn_sched_barrier(0);
    domfma();
    ldfrags(kt, 1);
    if (kt + 2 < NT) stage(kt + 2);
    __builtin_amdgcn_sched_barrier(0);
    if (kt + 2 < NT) asm volatile("s_waitcnt vmcnt(6)" ::: "memory");
    else             asm volatile("s_waitcnt vmcnt(0)" ::: "memory");
    __builtin_amdgcn_s_barrier();
    asm volatile("s_waitcnt lgkmcnt(0)" ::: "memory");
    __builtin_amdgcn_sched_barrier(0);
    domfma();
  }

#pragma unroll
  for (int f = 0; f < 4; ++f)
#pragma unroll
    for (int j = 0; j < 4; ++j) {
      const int n = n0 + no + j * 16 + fr;
#pragma unroll
      for (int r = 0; r < 4; ++r) {
        const int m = m0 + mo + f * 16 + rb + r;
        float v = acc[f][j][r];
        v = 1.f / (1.f + __expf(-v));
        if (n < DY_) out[(size_t)m * DY_ + n] = v;
        else         out2[(size_t)m * DY_ + (n - DY_)] = v;
      }
    }
}

extern "C" void kernel_launch(void* const* d_in, const int* in_sizes, int n_in,
                              void* d_out, int out_size, void* d_ws, size_t ws_size,
                              hipStream_t stream) {
  const float* xs  = (const float*)d_in[0];
  const float* Wx  = (const float*)d_in[1];
  const float* bx  = (const float*)d_in[2];
  const float* Wy  = (const float*)d_in[3];
  const float* by  = (const float*)d_in[4];
  const float* Wn  = (const float*)d_in[5];
  const float* bn  = (const float*)d_in[6];
  const float* Wu  = (const float*)d_in[7];
  const float* bu  = (const float*)d_in[8];
  const float* Wq  = (const float*)d_in[9];
  const float* bq  = (const float*)d_in[10];
  const float* ys0 = (const float*)d_in[11];
  const float* zs0 = (const float*)d_in[12];

  char* ws = (char*)d_ws;
  size_t off = 0;
  auto take = [&](size_t bytes) -> char* {
    char* p = ws + off;
    off += (bytes + 255) & ~(size_t)255;
    return p;
  };

  bf16*  Wn_b   = (bf16*)take((size_t)DZ_ * 3 * DZ_ * 2);
  bf16*  Wx_b   = (bf16*)take((size_t)DZ_ * DX_ * 2);
  bf16*  Wy_b   = (bf16*)take((size_t)DZ_ * DY_ * 2);
  bf16*  Wuq_b  = (bf16*)take((size_t)2 * DY_ * DZ_ * 2);
  float* buq    = (float*)take((size_t)2 * DY_ * 4);
  bf16*  ys_b   = (bf16*)take((size_t)B_ * DZ_ * 2);
  bf16*  z_a    = (bf16*)take((size_t)B_ * DZ_ * 2);
  bf16*  z_b    = (bf16*)take((size_t)B_ * DZ_ * 2);
  bf16*  xse_b  = (bf16*)take((size_t)B_ * DZ_ * 2);
  bf16*  xs_b   = (bf16*)take((size_t)B_ * DX_ * 2);
  bf16*  ysin_b = (bf16*)take((size_t)B_ * DY_ * 2);
  unsigned int* flags = (unsigned int*)take(32 * 32 * 4);

  auto cvt = [&](const float* src, bf16* dst, size_t n) {
    int n4 = (int)(n / 4);
    cvt_bf16_kernel<<<(n4 + 255) / 256, 256, 0, stream>>>(src, dst, n4);
  };
  cvt(Wn, Wn_b, (size_t)DZ_ * 3 * DZ_);
  cvt(Wx, Wx_b, (size_t)DZ_ * DX_);
  cvt(Wy, Wy_b, (size_t)DZ_ * DY_);
  cvt(Wu, Wuq_b, (size_t)DY_ * DZ_);
  cvt(Wq, Wuq_b + (size_t)DY_ * DZ_, (size_t)DY_ * DZ_);
  cvt(xs, xs_b, (size_t)B_ * DX_);
  cvt(ys0, ysin_b, (size_t)B_ * DY_);
  cvt(zs0, z_a, (size_t)B_ * DZ_);
  pack_bias_kernel<<<1, 512, 0, stream>>>(bu, bq, buq);
  hipMemsetAsync(flags, 0, 32 * 32 * 4, stream);   // re-zero every call (determinism)

  // persistent fused recurrence: 256 blocks = 1/CU, all co-resident
  trm_persist<<<dim3(32, 8), 512, 0, stream>>>(
      xs_b, ysin_b, z_a, z_b, Wx_b, Wy_b, Wn_b, bx, by, bn, xse_b, ys_b, flags);

  float* outp = (float*)d_out;
  head_gemm<<<dim3(32, 4), 512, 0, stream>>>(ys_b, Wuq_b, buq,
                                             outp, outp + (size_t)B_ * DY_);
}

// Round 9
// 924.646 us; speedup vs baseline: 1.7764x; 1.7764x over previous
//
#include <hip/hip_runtime.h>
#include <hip/hip_bf16.h>
#include <cstdint>
#include <cstddef>

#define B_   8192
#define DX_  512
#define DZ_  1024
#define DY_  256
#define T_   4
#define NN_  6

typedef float f32x4 __attribute__((ext_vector_type(4)));
typedef short s16x8 __attribute__((ext_vector_type(8)));
typedef __hip_bfloat16 bf16;

__device__ __forceinline__ void gload_lds16(const bf16* g, void* l) {
  __builtin_amdgcn_global_load_lds(
      (const __attribute__((address_space(1))) void*)g,
      (__attribute__((address_space(3))) void*)l,
      16, 0, 0);
}

__device__ __forceinline__ float bf2f(unsigned short u) {
  union { unsigned int i; float f; } cv; cv.i = ((unsigned int)u) << 16; return cv.f;
}

// ---- one fused conversion kernel: all fp32->bf16 copies + bias pack (saves 8 launches)
__device__ __forceinline__ void cv4(const float* __restrict__ s, bf16* __restrict__ d, long i) {
  float4 v = ((const float4*)s)[i];
  ushort4 o;
  bf16 a0 = __float2bfloat16(v.x); o.x = *(unsigned short*)&a0;
  bf16 a1 = __float2bfloat16(v.y); o.y = *(unsigned short*)&a1;
  bf16 a2 = __float2bfloat16(v.z); o.z = *(unsigned short*)&a2;
  bf16 a3 = __float2bfloat16(v.w); o.w = *(unsigned short*)&a3;
  ((ushort4*)d)[i] = o;
}

__global__ void cvt_all_kernel(const float* __restrict__ Wn, const float* __restrict__ Wx,
                               const float* __restrict__ Wy, const float* __restrict__ Wu,
                               const float* __restrict__ Wq, const float* __restrict__ xs,
                               const float* __restrict__ ys0, const float* __restrict__ zs0,
                               const float* __restrict__ bu, const float* __restrict__ bq,
                               bf16* __restrict__ Wn_b, bf16* __restrict__ Wx_b,
                               bf16* __restrict__ Wy_b, bf16* __restrict__ Wuq_b,
                               bf16* __restrict__ xs_b, bf16* __restrict__ ysin_b,
                               bf16* __restrict__ z_a, float* __restrict__ buq) {
  const long NWN = (long)DZ_ * 3 * DZ_ / 4, NWX = (long)DZ_ * DX_ / 4,
             NWY = (long)DZ_ * DY_ / 4,     NWU = (long)DY_ * DZ_ / 4,
             NXS = (long)B_ * DX_ / 4,      NYS = (long)B_ * DY_ / 4,
             NZS = (long)B_ * DZ_ / 4,      NBQ = 2 * DY_ / 4;
  const long total = NWN + NWX + NWY + 2 * NWU + NXS + NYS + NZS + NBQ;
  for (long i = (long)blockIdx.x * blockDim.x + threadIdx.x; i < total;
       i += (long)gridDim.x * blockDim.x) {
    long j = i;
    if (j < NWN) { cv4(Wn, Wn_b, j); continue; } j -= NWN;
    if (j < NWX) { cv4(Wx, Wx_b, j); continue; } j -= NWX;
    if (j < NWY) { cv4(Wy, Wy_b, j); continue; } j -= NWY;
    if (j < NWU) { cv4(Wu, Wuq_b, j); continue; } j -= NWU;
    if (j < NWU) { cv4(Wq, Wuq_b + (size_t)DY_ * DZ_ / 4 * 4, j); continue; } j -= NWU;
    if (j < NXS) { cv4(xs, xs_b, j); continue; } j -= NXS;
    if (j < NYS) { cv4(ys0, ysin_b, j); continue; } j -= NYS;
    if (j < NZS) { cv4(zs0, z_a, j); continue; } j -= NZS;
    // bias pack: float4 j of buq[512]
    float4 v;
    if (j < DY_ / 4) v = ((const float4*)bu)[j];
    else             v = ((const float4*)bq)[j - DY_ / 4];
    ((float4*)buq)[j] = v;
  }
}

// C[m,n] = act( preload + sum_k A[m,k]*W[n,k] ), preload = bias[n] (+ add1[m,n] if HASADD
// and MODE!=1; MODE1 re-reads add1 in the epilogue and also stores the pre-add value).
// MODE: 0 = bf16 out; 1 = bf16 out_pre (pre-add1) + bf16 out (post-add1); 2 = fp32 split head.
// BM=256 x BN=128, 512 threads (8 waves 4Mx2N, wave-tile 64x64), K-tile 64, three 48KB
// LDS buffers (144KB, 1 block/CU), stage distance 2.
// r9 schedule: ONE barrier + ONE counted vmcnt per K-tile. Both k-halves' 16 ds_reads
// issue up front; lgkmcnt(8) gates MFMA(half0), lgkmcnt(0) gates MFMA(half1) — MFMA
// execution drains under the next iteration's LDS burst (barrier syncs issue, not MFMA
// completion; acc reuse distance spans the burst). Buffer safety: stage(kt+2) overwrites
// tile kt-1's buffer, whose reads were drained by lgkmcnt(0) before the prior barrier.
// Chunk-XOR swizzle: linear gload_lds dest + permuted global source q = pos ^ (row&7)
// + same XOR on read (0 bank conflicts measured r2-r8).
template<int ACT, int MODE, bool HASADD>   // ACT: 0 none, 1 tanh, 2 sigmoid
__global__ __launch_bounds__(512, 2)
void gemm_bt(const bf16* __restrict__ A, int lda,
             const bf16* __restrict__ W, int ldw,
             const float* __restrict__ bias,
             const bf16* __restrict__ add1,
             bf16* __restrict__ out_pre,
             void* __restrict__ out, void* __restrict__ out2,
             int N, int K)
{
  __shared__ __align__(16) char ldsc[3 * 49152];   // [buf][A 32KB | B 16KB]
  const int t    = threadIdx.x;
  const int lane = t & 63;
  const int wave = t >> 6;
  const int m0 = blockIdx.x * 256;
  const int n0 = blockIdx.y * 128;

  // ---- staging: unit u = i*512 + t per gload; row = u>>3, pos = u&7 (16B chunks,
  // 8 per 128B row). Source-permuted chunk q = pos ^ (row&7); i*64 ≡ 0 mod 8 so q
  // is i-invariant.
  const int srow = t >> 3;                     // 0..63 (+64*i per gload)
  const int q    = (t & 7) ^ ((t >> 3) & 7);
  const bf16* gA = A + (size_t)(m0 + srow) * lda + q * 8;
  const bf16* gB = W + (size_t)(n0 + srow) * ldw + q * 8;
  const int wb = wave * 1024;                  // wave-uniform LDS dest base

  auto stage = [&](int kt) {                   // 6 gloads: A 4x8KB, B 2x8KB
    char* base = ldsc + (kt % 3) * 49152;
    const int ko = kt << 6;
#pragma unroll
    for (int i = 0; i < 4; ++i)
      gload_lds16(gA + (size_t)(i * 64) * lda + ko, base + i * 8192 + wb);
#pragma unroll
    for (int i = 0; i < 2; ++i)
      gload_lds16(gB + (size_t)(i * 64) * ldw + ko, base + 32768 + i * 8192 + wb);
  };

  // ---- fragment addressing: wave grid 4Mx2N, wave-tile 64x64 (4x4 frags 16x16x32)
  const int mo = (wave >> 1) * 64;
  const int no = (wave & 1) * 64;
  const int fr = lane & 15;                    // fragment row (A) / col (B)
  const int g4 = lane >> 4;                    // k sub-chunk 0..3
  const int rb = g4 * 4;                       // C/D row base

  const int NT = K >> 6;                       // K-tiles of 64: 4/8/16 here

  // ---- prologue loads: bias + addend first (drained by acc init), then tiles 0,1.
  float bv[4] = {0.f, 0.f, 0.f, 0.f};
  if (bias) {
#pragma unroll
    for (int j = 0; j < 4; ++j) bv[j] = bias[n0 + no + j * 16 + fr];
  }
  unsigned short adr[4][4][4];
  if (HASADD && MODE != 1) {
#pragma unroll
    for (int f = 0; f < 4; ++f)
#pragma unroll
      for (int j = 0; j < 4; ++j) {
        const unsigned short* p = (const unsigned short*)add1
            + (size_t)(m0 + mo + f * 16 + rb) * N + (n0 + no + j * 16 + fr);
#pragma unroll
        for (int r = 0; r < 4; ++r) adr[f][j][r] = p[(size_t)r * N];
      }
  }
  __builtin_amdgcn_sched_barrier(0);
  stage(0);
  stage(1);
  __builtin_amdgcn_sched_barrier(0);

  // ---- accumulator preload (compiler's waitcnt for adr drains addend loads only)
  f32x4 acc[4][4];
#pragma unroll
  for (int f = 0; f < 4; ++f)
#pragma unroll
    for (int j = 0; j < 4; ++j)
#pragma unroll
      for (int r = 0; r < 4; ++r) {
        float v = bv[j];
        if (HASADD && MODE != 1) v += bf2f(adr[f][j][r]);
        acc[f][j][r] = v;
      }

  // ---- frag sets (named; compile-time indices under unroll)
  s16x8 a0[4], b0[4], a1[4], b1[4];
  auto ldfrags = [&](int kt, int s, s16x8* fa, s16x8* fb) {
    const char* pA = ldsc + (kt % 3) * 49152;
    const char* pB = pA + 32768;
    const int cb = ((s * 4 + g4) ^ (fr & 7)) * 16;   // swizzled chunk byte offset
#pragma unroll
    for (int f = 0; f < 4; ++f) fa[f] = *(const s16x8*)(pA + (mo + f * 16 + fr) * 128 + cb);
#pragma unroll
    for (int j = 0; j < 4; ++j) fb[j] = *(const s16x8*)(pB + (no + j * 16 + fr) * 128 + cb);
  };
  auto domfma = [&](const s16x8* fa, const s16x8* fb) {
    __builtin_amdgcn_s_setprio(1);
#pragma unroll
    for (int f = 0; f < 4; ++f)
#pragma unroll
      for (int j = 0; j < 4; ++j)
        acc[f][j] = __builtin_amdgcn_mfma_f32_16x16x32_bf16(fa[f], fb[j], acc[f][j], 0, 0, 0);
    __builtin_amdgcn_s_setprio(0);
  };

  // tile 0 resident (tile 1's 6 loads may stay in flight)
  asm volatile("s_waitcnt vmcnt(6)" ::: "memory");
  __builtin_amdgcn_s_barrier();
  __builtin_amdgcn_sched_barrier(0);

  for (int kt = 0; kt < NT; ++kt) {
    // issue the whole K-tile's 16 ds_reads, then next-next tile's stage
    ldfrags(kt, 0, a0, b0);
    ldfrags(kt, 1, a1, b1);
    if (kt + 2 < NT) stage(kt + 2);
    __builtin_amdgcn_sched_barrier(0);
    asm volatile("s_waitcnt lgkmcnt(8)" ::: "memory");   // half-0 frags landed
    __builtin_amdgcn_sched_barrier(0);
    domfma(a0, b0);
    asm volatile("s_waitcnt lgkmcnt(0)" ::: "memory");   // half-1 frags landed
    __builtin_amdgcn_sched_barrier(0);
    domfma(a1, b1);
    // one counted vmcnt + one barrier per K-tile
    if (kt + 2 < NT)      asm volatile("s_waitcnt vmcnt(6)" ::: "memory");
    else if (kt + 1 < NT) asm volatile("s_waitcnt vmcnt(0)" ::: "memory");
    if (kt + 1 < NT) {
      __builtin_amdgcn_s_barrier();
      __builtin_amdgcn_sched_barrier(0);
    }
  }

  // ---- epilogue.  C/D layout: col = lane&15, row = (lane>>4)*4 + reg
#pragma unroll
  for (int f = 0; f < 4; ++f) {
#pragma unroll
    for (int j = 0; j < 4; ++j) {
      const int n = n0 + no + j * 16 + fr;
#pragma unroll
      for (int r = 0; r < 4; ++r) {
        const int m = m0 + mo + f * 16 + rb + r;
        float v = acc[f][j][r];
        if (MODE == 1) {
          out_pre[(size_t)m * N + n] = __float2bfloat16(v);
          v += bf2f(((const unsigned short*)add1)[(size_t)m * N + n]);
        }
        if (ACT == 1)      { float e = __expf(2.f * v); v = 1.f - 2.f / (e + 1.f); }
        else if (ACT == 2) v = 1.f / (1.f + __expf(-v));
        if (MODE == 2) {
          if (n < DY_) ((float*)out)[(size_t)m * DY_ + n] = v;
          else         ((float*)out2)[(size_t)m * DY_ + (n - DY_)] = v;
        } else {
          ((bf16*)out)[(size_t)m * N + n] = __float2bfloat16(v);
        }
      }
    }
  }
}

extern "C" void kernel_launch(void* const* d_in, const int* in_sizes, int n_in,
                              void* d_out, int out_size, void* d_ws, size_t ws_size,
                              hipStream_t stream) {
  const float* xs  = (const float*)d_in[0];
  const float* Wx  = (const float*)d_in[1];
  const float* bx  = (const float*)d_in[2];
  const float* Wy  = (const float*)d_in[3];
  const float* by  = (const float*)d_in[4];
  const float* Wn  = (const float*)d_in[5];
  const float* bn  = (const float*)d_in[6];
  const float* Wu  = (const float*)d_in[7];
  const float* bu  = (const float*)d_in[8];
  const float* Wq  = (const float*)d_in[9];
  const float* bq  = (const float*)d_in[10];
  const float* ys0 = (const float*)d_in[11];
  const float* zs0 = (const float*)d_in[12];

  char* ws = (char*)d_ws;
  size_t off = 0;
  auto take = [&](size_t bytes) -> char* {
    char* p = ws + off;
    off += (bytes + 255) & ~(size_t)255;
    return p;
  };

  bf16*  Wn_b   = (bf16*)take((size_t)DZ_ * 3 * DZ_ * 2);
  bf16*  Wx_b   = (bf16*)take((size_t)DZ_ * DX_ * 2);
  bf16*  Wy_b   = (bf16*)take((size_t)DZ_ * DY_ * 2);
  bf16*  Wuq_b  = (bf16*)take((size_t)2 * DY_ * DZ_ * 2);
  float* buq    = (float*)take((size_t)2 * DY_ * 4);
  bf16*  ys_b   = (bf16*)take((size_t)B_ * DZ_ * 2);
  bf16*  z_a    = (bf16*)take((size_t)B_ * DZ_ * 2);
  bf16*  z_b    = (bf16*)take((size_t)B_ * DZ_ * 2);
  bf16*  cx     = (bf16*)take((size_t)B_ * DZ_ * 2);
  bf16*  cy     = (bf16*)take((size_t)B_ * DZ_ * 2);
  bf16*  c      = (bf16*)take((size_t)B_ * DZ_ * 2);
  // aliases into regions not yet live at time of use:
  bf16* xs_b   = c;                                         // dead before c first written
  bf16* ysin_b = (bf16*)((char*)c + (size_t)B_ * DX_ * 2);  // 8.4+4.2 MB <= 16.7 MB
  bf16* xse_b  = cy;                                        // dead before cy first written

  // one fused conversion kernel (replaces 8 cvt launches + bias pack)
  cvt_all_kernel<<<2048, 256, 0, stream>>>(Wn, Wx, Wy, Wu, Wq, xs, ys0, zs0, bu, bq,
                                           Wn_b, Wx_b, Wy_b, Wuq_b,
                                           xs_b, ysin_b, z_a, buq);

  const dim3 blk(512);
  const dim3 gz(B_ / 256, DZ_ / 128);   // 32 x 8 = 256 blocks = 1/CU
  const dim3 gh(B_ / 256, 4);           // head: N=512 -> 32 x 4

  // xs_e = xs@Wx.T + bx  (bf16)
  gemm_bt<0, 0, false><<<gz, blk, 0, stream>>>(xs_b, DX_, Wx_b, DX_, bx, nullptr, nullptr, xse_b, nullptr, DZ_, DX_);
  // ys_e = ys0@Wy.T + by (bf16)
  gemm_bt<0, 0, false><<<gz, blk, 0, stream>>>(ysin_b, DY_, Wy_b, DY_, by, nullptr, nullptr, ys_b, nullptr, DZ_, DY_);
  // cx = xs_e@Wnx.T (bf16)
  gemm_bt<0, 0, false><<<gz, blk, 0, stream>>>(xse_b, DZ_, Wn_b, 3 * DZ_, nullptr, nullptr, nullptr, cx, nullptr, DZ_, DZ_);

  bf16* zc = z_a;
  bf16* zn = z_b;
  for (int tt = 0; tt < T_; ++tt) {
    // cy = ys_e@Wny.T + bn ; c = cy + cx  (both bf16, one GEMM)
    gemm_bt<0, 1, true><<<gz, blk, 0, stream>>>(ys_b, DZ_, Wn_b + DZ_, 3 * DZ_, bn, cx, cy, c, nullptr, DZ_, DZ_);
    for (int i = 0; i < NN_; ++i) {
      // z = tanh(c + z@Wnz.T)   (addend preloaded into acc)
      gemm_bt<1, 0, true><<<gz, blk, 0, stream>>>(zc, DZ_, Wn_b + 2 * DZ_, 3 * DZ_, nullptr, c, nullptr, zn, nullptr, DZ_, DZ_);
      bf16* tmp = zc; zc = zn; zn = tmp;
    }
    // ys_e = tanh(cy + z@Wnz.T)
    gemm_bt<1, 0, true><<<gz, blk, 0, stream>>>(zc, DZ_, Wn_b + 2 * DZ_, 3 * DZ_, nullptr, cy, nullptr, ys_b, nullptr, DZ_, DZ_);
  }

  float* outp = (float*)d_out;
  // y_hat | q_hat = sigmoid(ys_e@[Wu;Wq].T + [bu;bq]) — one N=512 GEMM, split store
  gemm_bt<2, 2, false><<<gh, blk, 0, stream>>>(ys_b, DZ_, Wuq_b, DZ_, buq, nullptr, nullptr,
                                               outp, outp + (size_t)B_ * DY_, 2 * DY_, DZ_);
}

// Round 10
// 828.926 us; speedup vs baseline: 1.9815x; 1.1155x over previous
//
#include <hip/hip_runtime.h>
#include <hip/hip_bf16.h>
#include <cstdint>
#include <cstddef>

#define B_   8192
#define DX_  512
#define DZ_  1024
#define DY_  256
#define T_   4
#define NN_  6

typedef float f32x4 __attribute__((ext_vector_type(4)));
typedef short s16x8 __attribute__((ext_vector_type(8)));
typedef long i64x2 __attribute__((ext_vector_type(2)));
typedef __hip_bfloat16 bf16;

__device__ __forceinline__ void gload_lds16(const void* g, void* l) {
  __builtin_amdgcn_global_load_lds(
      (const __attribute__((address_space(1))) void*)g,
      (__attribute__((address_space(3))) void*)l,
      16, 0, 0);
}

__device__ __forceinline__ float bf2f(unsigned short u) {
  union { unsigned int i; float f; } cv; cv.i = ((unsigned int)u) << 16; return cv.f;
}

// fp8 k-permute: within each 64-col group, byte for col n goes to
// perm(n) = g4*16 + slice*8 + j  (g4=(n>>3)&3, slice=(n>>5)&1, j=n&7), so a b128
// LDS read at chunk g4 yields both K=32 slices for mfma_16x16x32_fp8_fp8.
__device__ __forceinline__ int permb(int n) {
  return (n & ~63) | (((n >> 3) & 3) << 4) | (((n >> 5) & 1) << 3) | (n & 7);
}

// ---- one fused conversion kernel: fp32->bf16 copies + bias pack + fp8 images
__device__ __forceinline__ void cv4(const float* __restrict__ s, bf16* __restrict__ d, long i) {
  float4 v = ((const float4*)s)[i];
  ushort4 o;
  bf16 a0 = __float2bfloat16(v.x); o.x = *(unsigned short*)&a0;
  bf16 a1 = __float2bfloat16(v.y); o.y = *(unsigned short*)&a1;
  bf16 a2 = __float2bfloat16(v.z); o.z = *(unsigned short*)&a2;
  bf16 a3 = __float2bfloat16(v.w); o.w = *(unsigned short*)&a3;
  ((ushort4*)d)[i] = o;
}
__device__ __forceinline__ void cv4f8(const float* __restrict__ src, unsigned char* __restrict__ dst,
                                      long row, int k0, int srcld, int srcoff) {
  float4 v = *(const float4*)(src + row * srcld + srcoff + k0);
  int p = __builtin_amdgcn_cvt_pk_fp8_f32(v.x, v.y, 0, 0);
  p = __builtin_amdgcn_cvt_pk_fp8_f32(v.z, v.w, p, 1);
  *(int*)(dst + row * DZ_ + permb(k0)) = p;   // k0 % 4 == 0 -> 4 contiguous bytes
}

__global__ void cvt_all_kernel(const float* __restrict__ Wn, const float* __restrict__ Wx,
                               const float* __restrict__ Wy, const float* __restrict__ Wu,
                               const float* __restrict__ Wq, const float* __restrict__ xs,
                               const float* __restrict__ ys0, const float* __restrict__ zs0,
                               const float* __restrict__ bu, const float* __restrict__ bq,
                               bf16* __restrict__ Wn_b, bf16* __restrict__ Wx_b,
                               bf16* __restrict__ Wy_b, bf16* __restrict__ Wuq_b,
                               bf16* __restrict__ xs_b, bf16* __restrict__ ysin_b,
                               bf16* __restrict__ z_a, float* __restrict__ buq,
                               unsigned char* __restrict__ Wnz8, unsigned char* __restrict__ z_a8) {
  const long NWN = (long)DZ_ * 3 * DZ_ / 4, NWX = (long)DZ_ * DX_ / 4,
             NWY = (long)DZ_ * DY_ / 4,     NWU = (long)DY_ * DZ_ / 4,
             NXS = (long)B_ * DX_ / 4,      NYS = (long)B_ * DY_ / 4,
             NZS = (long)B_ * DZ_ / 4,      NBQ = 2 * DY_ / 4,
             NW8 = (long)DZ_ * DZ_ / 4,     NZ8 = (long)B_ * DZ_ / 4;
  const long total = NWN + NWX + NWY + 2 * NWU + NXS + NYS + NZS + NBQ + NW8 + NZ8;
  for (long i = (long)blockIdx.x * blockDim.x + threadIdx.x; i < total;
       i += (long)gridDim.x * blockDim.x) {
    long j = i;
    if (j < NWN) { cv4(Wn, Wn_b, j); continue; } j -= NWN;
    if (j < NWX) { cv4(Wx, Wx_b, j); continue; } j -= NWX;
    if (j < NWY) { cv4(Wy, Wy_b, j); continue; } j -= NWY;
    if (j < NWU) { cv4(Wu, Wuq_b, j); continue; } j -= NWU;
    if (j < NWU) { cv4(Wq, Wuq_b + (size_t)DY_ * DZ_, j); continue; } j -= NWU;
    if (j < NXS) { cv4(xs, xs_b, j); continue; } j -= NXS;
    if (j < NYS) { cv4(ys0, ysin_b, j); continue; } j -= NYS;
    if (j < NZS) { cv4(zs0, z_a, j); continue; } j -= NZS;
    if (j < NBQ) {
      float4 v = (j < DY_ / 4) ? ((const float4*)bu)[j] : ((const float4*)bq)[j - DY_ / 4];
      ((float4*)buq)[j] = v; continue;
    } j -= NBQ;
    if (j < NW8) {  // Wnz (cols 2048..3071 of Wn) -> fp8 k-permuted
      long e = j * 4; long row = e >> 10; int k0 = (int)(e & 1023);
      cv4f8(Wn, Wnz8, row, k0, 3 * DZ_, 2 * DZ_); continue;
    } j -= NW8;
    {   // zs0 -> fp8 k-permuted
      long e = j * 4; long row = e >> 10; int k0 = (int)(e & 1023);
      cv4f8(zs0, z_a8, row, k0, DZ_, 0);
    }
  }
}

// ================= bf16 GEMM (r9-proven, unchanged) =================
template<int ACT, int MODE, bool HASADD>   // ACT: 0 none, 1 tanh, 2 sigmoid
__global__ __launch_bounds__(512, 2)
void gemm_bt(const bf16* __restrict__ A, int lda,
             const bf16* __restrict__ W, int ldw,
             const float* __restrict__ bias,
             const bf16* __restrict__ add1,
             bf16* __restrict__ out_pre,
             void* __restrict__ out, void* __restrict__ out2,
             int N, int K)
{
  __shared__ __align__(16) char ldsc[3 * 49152];   // [buf][A 32KB | B 16KB]
  const int t    = threadIdx.x;
  const int lane = t & 63;
  const int wave = t >> 6;
  const int m0 = blockIdx.x * 256;
  const int n0 = blockIdx.y * 128;

  const int srow = t >> 3;
  const int q    = (t & 7) ^ ((t >> 3) & 7);
  const bf16* gA = A + (size_t)(m0 + srow) * lda + q * 8;
  const bf16* gB = W + (size_t)(n0 + srow) * ldw + q * 8;
  const int wb = wave * 1024;

  auto stage = [&](int kt) {
    char* base = ldsc + (kt % 3) * 49152;
    const int ko = kt << 6;
#pragma unroll
    for (int i = 0; i < 4; ++i)
      gload_lds16(gA + (size_t)(i * 64) * lda + ko, base + i * 8192 + wb);
#pragma unroll
    for (int i = 0; i < 2; ++i)
      gload_lds16(gB + (size_t)(i * 64) * ldw + ko, base + 32768 + i * 8192 + wb);
  };

  const int mo = (wave >> 1) * 64;
  const int no = (wave & 1) * 64;
  const int fr = lane & 15;
  const int g4 = lane >> 4;
  const int rb = g4 * 4;

  const int NT = K >> 6;

  float bv[4] = {0.f, 0.f, 0.f, 0.f};
  if (bias) {
#pragma unroll
    for (int j = 0; j < 4; ++j) bv[j] = bias[n0 + no + j * 16 + fr];
  }
  unsigned short adr[4][4][4];
  if (HASADD && MODE != 1) {
#pragma unroll
    for (int f = 0; f < 4; ++f)
#pragma unroll
      for (int j = 0; j < 4; ++j) {
        const unsigned short* p = (const unsigned short*)add1
            + (size_t)(m0 + mo + f * 16 + rb) * N + (n0 + no + j * 16 + fr);
#pragma unroll
        for (int r = 0; r < 4; ++r) adr[f][j][r] = p[(size_t)r * N];
      }
  }
  __builtin_amdgcn_sched_barrier(0);
  stage(0);
  stage(1);
  __builtin_amdgcn_sched_barrier(0);

  f32x4 acc[4][4];
#pragma unroll
  for (int f = 0; f < 4; ++f)
#pragma unroll
    for (int j = 0; j < 4; ++j)
#pragma unroll
      for (int r = 0; r < 4; ++r) {
        float v = bv[j];
        if (HASADD && MODE != 1) v += bf2f(adr[f][j][r]);
        acc[f][j][r] = v;
      }

  s16x8 a0[4], b0[4], a1[4], b1[4];
  auto ldfrags = [&](int kt, int s, s16x8* fa, s16x8* fb) {
    const char* pA = ldsc + (kt % 3) * 49152;
    const char* pB = pA + 32768;
    const int cb = ((s * 4 + g4) ^ (fr & 7)) * 16;
#pragma unroll
    for (int f = 0; f < 4; ++f) fa[f] = *(const s16x8*)(pA + (mo + f * 16 + fr) * 128 + cb);
#pragma unroll
    for (int j = 0; j < 4; ++j) fb[j] = *(const s16x8*)(pB + (no + j * 16 + fr) * 128 + cb);
  };
  auto domfma = [&](const s16x8* fa, const s16x8* fb) {
    __builtin_amdgcn_s_setprio(1);
#pragma unroll
    for (int f = 0; f < 4; ++f)
#pragma unroll
      for (int j = 0; j < 4; ++j)
        acc[f][j] = __builtin_amdgcn_mfma_f32_16x16x32_bf16(fa[f], fb[j], acc[f][j], 0, 0, 0);
    __builtin_amdgcn_s_setprio(0);
  };

  asm volatile("s_waitcnt vmcnt(6)" ::: "memory");
  __builtin_amdgcn_s_barrier();
  __builtin_amdgcn_sched_barrier(0);

  for (int kt = 0; kt < NT; ++kt) {
    ldfrags(kt, 0, a0, b0);
    ldfrags(kt, 1, a1, b1);
    if (kt + 2 < NT) stage(kt + 2);
    __builtin_amdgcn_sched_barrier(0);
    asm volatile("s_waitcnt lgkmcnt(8)" ::: "memory");
    __builtin_amdgcn_sched_barrier(0);
    domfma(a0, b0);
    asm volatile("s_waitcnt lgkmcnt(0)" ::: "memory");
    __builtin_amdgcn_sched_barrier(0);
    domfma(a1, b1);
    if (kt + 2 < NT)      asm volatile("s_waitcnt vmcnt(6)" ::: "memory");
    else if (kt + 1 < NT) asm volatile("s_waitcnt vmcnt(0)" ::: "memory");
    if (kt + 1 < NT) {
      __builtin_amdgcn_s_barrier();
      __builtin_amdgcn_sched_barrier(0);
    }
  }

#pragma unroll
  for (int f = 0; f < 4; ++f) {
#pragma unroll
    for (int j = 0; j < 4; ++j) {
      const int n = n0 + no + j * 16 + fr;
#pragma unroll
      for (int r = 0; r < 4; ++r) {
        const int m = m0 + mo + f * 16 + rb + r;
        float v = acc[f][j][r];
        if (MODE == 1) {
          out_pre[(size_t)m * N + n] = __float2bfloat16(v);
          v += bf2f(((const unsigned short*)add1)[(size_t)m * N + n]);
        }
        if (ACT == 1)      { float e = __expf(2.f * v); v = 1.f - 2.f / (e + 1.f); }
        else if (ACT == 2) v = 1.f / (1.f + __expf(-v));
        if (MODE == 2) {
          if (n < DY_) ((float*)out)[(size_t)m * DY_ + n] = v;
          else         ((float*)out2)[(size_t)m * DY_ + (n - DY_)] = v;
        } else {
          ((bf16*)out)[(size_t)m * N + n] = __float2bfloat16(v);
        }
      }
    }
  }
}

// ================= fp8 z-step GEMM =================
// z_next = tanh(c + z @ Wnz.T), A/W fp8 e4m3 in k-permuted global layout.
// Same structure as gemm_bt but half the bytes: 24KB/tile, 4-buffer rotation (96KB),
// prefetch depth 3, 8 b128 frag reads per wave per K-64 (both K=32 slices per read).
// Chunk-XOR swizzle for 64B rows: source q = pos ^ ((row>>1)&3), read cb = g4 ^ ((fr>>1)&3)
// (r6-verified involution). Writes fp8 (permuted) always; bf16 shadow only if out16.
__global__ __launch_bounds__(512, 2)
void gemm_f8(const unsigned char* __restrict__ A8,
             const unsigned char* __restrict__ W8,
             const bf16* __restrict__ add1,
             unsigned char* __restrict__ out8,
             bf16* __restrict__ out16)
{
  __shared__ __align__(16) char ldsc[4 * 24576];   // [buf][A 16KB | B 8KB]
  const int t    = threadIdx.x;
  const int lane = t & 63;
  const int wave = t >> 6;
  const int m0 = blockIdx.x * 256;
  const int n0 = blockIdx.y * 128;

  // staging: 16B unit u=t per gload; row = t>>2 (0..127), pos = t&3; q = pos ^ ((row>>1)&3)
  const int srow = t >> 2;
  const int q    = (t & 3) ^ ((t >> 3) & 3);
  const unsigned char* gA = A8 + (size_t)(m0 + srow) * DZ_ + q * 16;
  const unsigned char* gB = W8 + (size_t)(n0 + srow) * DZ_ + q * 16;
  const int wb = wave * 1024;

  auto stage = [&](int kt) {                 // 3 gloads: A 2x8KB, B 1x8KB
    char* base = ldsc + (kt & 3) * 24576;
    const int ko = kt << 6;
    gload_lds16(gA + ko, base + wb);
    gload_lds16(gA + (size_t)128 * DZ_ + ko, base + 8192 + wb);
    gload_lds16(gB + ko, base + 16384 + wb);
  };

  const int mo = (wave >> 1) * 64;
  const int no = (wave & 1) * 64;
  const int fr = lane & 15;
  const int g4 = lane >> 4;
  const int rb = g4 * 4;
  const int cb = (g4 ^ ((fr >> 1) & 3)) * 16;   // swizzled 16B chunk

  const int NT = DZ_ >> 6;                      // 16

  // addend preload (c, bf16)
  unsigned short adr[4][4][4];
#pragma unroll
  for (int f = 0; f < 4; ++f)
#pragma unroll
    for (int j = 0; j < 4; ++j) {
      const unsigned short* p = (const unsigned short*)add1
          + (size_t)(m0 + mo + f * 16 + rb) * DZ_ + (n0 + no + j * 16 + fr);
#pragma unroll
      for (int r = 0; r < 4; ++r) adr[f][j][r] = p[(size_t)r * DZ_];
    }
  __builtin_amdgcn_sched_barrier(0);
  stage(0); stage(1); stage(2);
  __builtin_amdgcn_sched_barrier(0);

  f32x4 acc[4][4];
#pragma unroll
  for (int f = 0; f < 4; ++f)
#pragma unroll
    for (int j = 0; j < 4; ++j)
#pragma unroll
      for (int r = 0; r < 4; ++r) acc[f][j][r] = bf2f(adr[f][j][r]);

  asm volatile("s_waitcnt vmcnt(6)" ::: "memory");   // tile 0 resident
  __builtin_amdgcn_s_barrier();
  __builtin_amdgcn_sched_barrier(0);

  for (int kt = 0; kt < NT; ++kt) {
    const char* pA = ldsc + (kt & 3) * 24576;
    const char* pB = pA + 16384;
    i64x2 av[4], bv[4];
#pragma unroll
    for (int f = 0; f < 4; ++f) av[f] = *(const i64x2*)(pA + (mo + f * 16 + fr) * 64 + cb);
#pragma unroll
    for (int j = 0; j < 4; ++j) bv[j] = *(const i64x2*)(pB + (no + j * 16 + fr) * 64 + cb);
    if (kt + 3 < NT) stage(kt + 3);
    __builtin_amdgcn_sched_barrier(0);
    asm volatile("s_waitcnt lgkmcnt(0)" ::: "memory");
    __builtin_amdgcn_sched_barrier(0);
    __builtin_amdgcn_s_setprio(1);
#pragma unroll
    for (int f = 0; f < 4; ++f)
#pragma unroll
      for (int j = 0; j < 4; ++j) {
        acc[f][j] = __builtin_amdgcn_mfma_f32_16x16x32_fp8_fp8(av[f][0], bv[j][0], acc[f][j], 0, 0, 0);
        acc[f][j] = __builtin_amdgcn_mfma_f32_16x16x32_fp8_fp8(av[f][1], bv[j][1], acc[f][j], 0, 0, 0);
      }
    __builtin_amdgcn_s_setprio(0);
    const int rem = NT - 1 - kt;
    if (rem >= 3)      asm volatile("s_waitcnt vmcnt(6)" ::: "memory");
    else if (rem == 2) asm volatile("s_waitcnt vmcnt(3)" ::: "memory");
    else if (rem == 1) asm volatile("s_waitcnt vmcnt(0)" ::: "memory");
    if (rem >= 1) {
      __builtin_amdgcn_s_barrier();
      __builtin_amdgcn_sched_barrier(0);
    }
  }

  // epilogue: tanh, fp8 (permuted) always; bf16 shadow optional
#pragma unroll
  for (int f = 0; f < 4; ++f) {
#pragma unroll
    for (int j = 0; j < 4; ++j) {
      const int n = n0 + no + j * 16 + fr;
      const int np = permb(n);
#pragma unroll
      for (int r = 0; r < 4; ++r) {
        const int m = m0 + mo + f * 16 + rb + r;
        float v = acc[f][j][r];
        float e = __expf(2.f * v); v = 1.f - 2.f / (e + 1.f);
        out8[(size_t)m * DZ_ + np] =
            (unsigned char)__builtin_amdgcn_cvt_pk_fp8_f32(v, v, 0, 0);
        if (out16) out16[(size_t)m * DZ_ + n] = __float2bfloat16(v);
      }
    }
  }
}

extern "C" void kernel_launch(void* const* d_in, const int* in_sizes, int n_in,
                              void* d_out, int out_size, void* d_ws, size_t ws_size,
                              hipStream_t stream) {
  const float* xs  = (const float*)d_in[0];
  const float* Wx  = (const float*)d_in[1];
  const float* bx  = (const float*)d_in[2];
  const float* Wy  = (const float*)d_in[3];
  const float* by  = (const float*)d_in[4];
  const float* Wn  = (const float*)d_in[5];
  const float* bn  = (const float*)d_in[6];
  const float* Wu  = (const float*)d_in[7];
  const float* bu  = (const float*)d_in[8];
  const float* Wq  = (const float*)d_in[9];
  const float* bq  = (const float*)d_in[10];
  const float* ys0 = (const float*)d_in[11];
  const float* zs0 = (const float*)d_in[12];

  char* ws = (char*)d_ws;
  size_t off = 0;
  auto take = [&](size_t bytes) -> char* {
    char* p = ws + off;
    off += (bytes + 255) & ~(size_t)255;
    return p;
  };

  bf16*  Wn_b   = (bf16*)take((size_t)DZ_ * 3 * DZ_ * 2);
  bf16*  Wx_b   = (bf16*)take((size_t)DZ_ * DX_ * 2);
  bf16*  Wy_b   = (bf16*)take((size_t)DZ_ * DY_ * 2);
  bf16*  Wuq_b  = (bf16*)take((size_t)2 * DY_ * DZ_ * 2);
  float* buq    = (float*)take((size_t)2 * DY_ * 4);
  bf16*  ys_b   = (bf16*)take((size_t)B_ * DZ_ * 2);
  bf16*  z_a    = (bf16*)take((size_t)B_ * DZ_ * 2);
  bf16*  z_b    = (bf16*)take((size_t)B_ * DZ_ * 2);
  bf16*  cx     = (bf16*)take((size_t)B_ * DZ_ * 2);
  bf16*  cy     = (bf16*)take((size_t)B_ * DZ_ * 2);
  bf16*  c      = (bf16*)take((size_t)B_ * DZ_ * 2);
  unsigned char* Wnz8 = (unsigned char*)take((size_t)DZ_ * DZ_);
  unsigned char* z_a8 = (unsigned char*)take((size_t)B_ * DZ_);
  unsigned char* z_b8 = (unsigned char*)take((size_t)B_ * DZ_);
  // aliases into regions not yet live at time of use:
  bf16* xs_b   = c;                                         // dead before c first written
  bf16* ysin_b = (bf16*)((char*)c + (size_t)B_ * DX_ * 2);  // 8.4+4.2 MB <= 16.7 MB
  bf16* xse_b  = cy;                                        // dead before cy first written

  cvt_all_kernel<<<2048, 256, 0, stream>>>(Wn, Wx, Wy, Wu, Wq, xs, ys0, zs0, bu, bq,
                                           Wn_b, Wx_b, Wy_b, Wuq_b,
                                           xs_b, ysin_b, z_a, buq, Wnz8, z_a8);

  const dim3 blk(512);
  const dim3 gz(B_ / 256, DZ_ / 128);   // 32 x 8 = 256 blocks = 1/CU
  const dim3 gh(B_ / 256, 4);           // head: N=512 -> 32 x 4

  // xs_e = xs@Wx.T + bx  (bf16)
  gemm_bt<0, 0, false><<<gz, blk, 0, stream>>>(xs_b, DX_, Wx_b, DX_, bx, nullptr, nullptr, xse_b, nullptr, DZ_, DX_);
  // ys_e = ys0@Wy.T + by (bf16)
  gemm_bt<0, 0, false><<<gz, blk, 0, stream>>>(ysin_b, DY_, Wy_b, DY_, by, nullptr, nullptr, ys_b, nullptr, DZ_, DY_);
  // cx = xs_e@Wnx.T (bf16)
  gemm_bt<0, 0, false><<<gz, blk, 0, stream>>>(xse_b, DZ_, Wn_b, 3 * DZ_, nullptr, nullptr, nullptr, cx, nullptr, DZ_, DZ_);

  bf16* zc = z_a;            // bf16 z shadow (valid at tt boundaries)
  bf16* zn = z_b;
  unsigned char* zc8 = z_a8; // fp8 z chain (no-grad phase)
  unsigned char* zn8 = z_b8;
  for (int tt = 0; tt < T_; ++tt) {
    // cy = ys_e@Wny.T + bn ; c = cy + cx  (bf16, one GEMM)
    gemm_bt<0, 1, true><<<gz, blk, 0, stream>>>(ys_b, DZ_, Wn_b + DZ_, 3 * DZ_, bn, cx, cy, c, nullptr, DZ_, DZ_);
    if (tt < T_ - 1) {
      // no-grad phase: fp8 z-steps; bf16 shadow written only on the last step
      for (int i = 0; i < NN_; ++i) {
        gemm_f8<<<gz, blk, 0, stream>>>(zc8, Wnz8, c, zn8, (i == NN_ - 1) ? zn : nullptr);
        unsigned char* t8 = zc8; zc8 = zn8; zn8 = t8;
      }
      bf16* tmp = zc; zc = zn; zn = tmp;   // shadow now in zc
    } else {
      // grad-enabled block: bf16 z-steps
      for (int i = 0; i < NN_; ++i) {
        gemm_bt<1, 0, true><<<gz, blk, 0, stream>>>(zc, DZ_, Wn_b + 2 * DZ_, 3 * DZ_, nullptr, c, nullptr, zn, nullptr, DZ_, DZ_);
        bf16* tmp = zc; zc = zn; zn = tmp;
      }
    }
    // ys_e = tanh(cy + z@Wnz.T)  (bf16, reads z shadow)
    gemm_bt<1, 0, true><<<gz, blk, 0, stream>>>(zc, DZ_, Wn_b + 2 * DZ_, 3 * DZ_, nullptr, cy, nullptr, ys_b, nullptr, DZ_, DZ_);
  }

  float* outp = (float*)d_out;
  // y_hat | q_hat = sigmoid(ys_e@[Wu;Wq].T + [bu;bq]) — one N=512 GEMM, split store
  gemm_bt<2, 2, false><<<gh, blk, 0, stream>>>(ys_b, DZ_, Wuq_b, DZ_, buq, nullptr, nullptr,
                                               outp, outp + (size_t)B_ * DY_, 2 * DY_, DZ_);
}